// Round 2
// baseline (242.208 us; speedup 1.0000x reference)
//
#include <hip/hip_runtime.h>
#include <cstdint>
#include <cmath>

#define B_ 4
#define H_ 256
#define C_ 80
#define TX_ 256
#define TY_ 1024
#define NEGF (-1e9f)

// output layout (floats): o_en_ex [B,H,TY] | logp [B,TX,TY] | attn [B,TX,TY] | dr [B,TX]
#define OFF_LOGP (B_*H_*TY_)
#define OFF_ATTN (OFF_LOGP + B_*TX_*TY_)
#define OFF_DR   (OFF_ATTN + B_*TX_*TY_)

// __shfl_up(x,1) as pure VALU: DPP wave_shr:1 (ctrl 0x138); lane 0 gets NEGF.
__device__ __forceinline__ float dpp_shr1_negfill_f32(float x) {
  union { float f; int i; } u, o, r;
  u.f = x; o.f = NEGF;
  r.i = __builtin_amdgcn_update_dpp(o.i, u.i, 0x138, 0xf, 0xf, false);
  return r.f;
}

// ---------------------------------------------------------------------------
// Kernel A: logp (unchanged, passing since R5).
// ---------------------------------------------------------------------------
__global__ __launch_bounds__(256) void k_logp(
    const float* __restrict__ mu, const float* __restrict__ ls,
    const float* __restrict__ y, const int* __restrict__ xlp,
    const int* __restrict__ ylp, float* __restrict__ logp_out,
    float* __restrict__ lpT)
{
  const int b  = blockIdx.y;
  const int x0 = blockIdx.x * 4;
  const int tid = threadIdx.x;
  __shared__ double s_w[4][C_];
  __shared__ double s_m1[4][C_];
  __shared__ double s_wm2[4][C_];
  __shared__ double s_lsv[4][C_];
  __shared__ double s_K[4];
  __shared__ double s_t0[4];
  __shared__ float tile[TY_][4];
  for (int i = tid; i < 4 * C_; i += 256) {
    int xi = i / C_, c = i - xi * C_;
    double m = (double)mu[(b * C_ + c) * TX_ + x0 + xi];
    double l = (double)ls[(b * C_ + c) * TX_ + x0 + xi];
    double w = exp(-2.0 * l);
    s_w[xi][c]   = w;
    s_m1[xi][c]  = -2.0 * w * m;
    s_wm2[xi][c] = w * m * m;
    s_lsv[xi][c] = l;
  }
  __syncthreads();
  {
    int xi = tid >> 6, cc = tid & 63;
    double kp = (cc < C_) ? s_wm2[xi][cc] : 0.0;
    double tp = (cc < C_) ? s_lsv[xi][cc] : 0.0;
    if (cc + 64 < C_) { kp += s_wm2[xi][cc + 64]; tp += s_lsv[xi][cc + 64]; }
#pragma unroll
    for (int off = 32; off; off >>= 1) {
      kp += __shfl_down(kp, off);
      tp += __shfl_down(tp, off);
    }
    if (cc == 0) { s_K[xi] = kp; s_t0[xi] = -0.5 * (tp * (1.0 / C_)); }
  }
  __syncthreads();

  const int t0 = tid * 4;
  double acc[4][4];
#pragma unroll
  for (int xi = 0; xi < 4; ++xi)
#pragma unroll
    for (int k = 0; k < 4; ++k) acc[xi][k] = 0.0;

  const float4* yp = (const float4*)(y + (size_t)b * C_ * TY_) + tid;
#pragma unroll 4
  for (int c = 0; c < C_; ++c) {
    float4 yv = yp[c * (TY_ / 4)];
    double y0 = yv.x, y1 = yv.y, y2 = yv.z, y3 = yv.w;
#pragma unroll
    for (int xi = 0; xi < 4; ++xi) {
      double w = s_w[xi][c], m1 = s_m1[xi][c];
      double u0 = fma(w, y0, m1), u1 = fma(w, y1, m1);
      double u2 = fma(w, y2, m1), u3 = fma(w, y3, m1);
      acc[xi][0] = fma(u0, y0, acc[xi][0]);
      acc[xi][1] = fma(u1, y1, acc[xi][1]);
      acc[xi][2] = fma(u2, y2, acc[xi][2]);
      acc[xi][3] = fma(u3, y3, acc[xi][3]);
    }
  }

  const int xlen = xlp[b], ylen = ylp[b];
#pragma unroll
  for (int xi = 0; xi < 4; ++xi) {
    int x = x0 + xi;
    double c0 = s_t0[xi], K = s_K[xi];
    float r[4];
#pragma unroll
    for (int k = 0; k < 4; ++k)
      r[k] = (float)((acc[xi][k] + K) * (-0.5 / C_) + c0);
    *(float4*)&logp_out[((size_t)(b * TX_ + x)) * TY_ + t0] =
        make_float4(r[0], r[1], r[2], r[3]);
    bool xm = x < xlen;
#pragma unroll
    for (int k = 0; k < 4; ++k)
      tile[t0 + k][xi] = (xm && (t0 + k) < ylen) ? r[k] : NEGF;
  }
  __syncthreads();

  float* dst = lpT + (size_t)b * TY_ * TX_ + x0;
  const float4* tp = (const float4*)tile;
#pragma unroll
  for (int k = 0; k < 4; ++k) {
    int t = tid + 256 * k;
    *(float4*)&dst[(size_t)t * TX_] = tp[t];
  }
}

// ---------------------------------------------------------------------------
// Kernel B (R15): producer-consumer Viterbi DP.
//
// R14 post-mortem: single wave + 16-deep register prefetch still stalled
// ~107 cyc/step on VMEM (VALUBusy_active ~11%).  16 outstanding 1KB loads
// = 256 line-fills per wave -> per-WAVE miss parallelism is the wall, not
// vmcnt discipline, not barriers (both falsified R13/R14).  Fix: the DP
// wave never touches global memory.  4 waves: wave 0 = consumer (DP from
// LDS ring), waves 1-3 = producers (global->reg->LDS, 2 chunks ahead).
//
// Ring: 3 slots x 32 rows x 1KB = 96KB.  Round g: consumer reads slot
// g%3 (rows 0..31) and slot (g+1)%3 (rows 0..3, reg prefetch); producers
// write slot (g+2)%3 -- all distinct mod 3.  One __syncthreads per round;
// its implicit vmcnt(0) drain lands on producers, who have ~2 rounds of
// slack -> consumer never waits on VMEM.
//
// Math bit-identical to R14: m = fmaxf(v, sh); nv = col + m;
// diag bit = signbit(v - m) <=> (sh > v) strict.  bits layout unchanged;
// backtrack/scan/scatter carried over verbatim.
// LDS: ring 96KB + bits 32KB + dur 1KB = 129KB (one block/CU).
// ---------------------------------------------------------------------------
__global__ __launch_bounds__(256, 1) void k_dp(
    const float* __restrict__ lpT, const int* __restrict__ xlp,
    const int* __restrict__ ylp, float* __restrict__ dr_out,
    int* __restrict__ cum_ws, int* __restrict__ xt_ws)
{
  const int b = blockIdx.x;
  const int tid = threadIdx.x;
  const int lane = tid & 63;
  const int w = tid >> 6;                 // wave id: 0 consumer, 1..3 producers
  __shared__ __align__(16) float    ring[3 * 32 * 256];  // 96 KB
  __shared__ __align__(16) uint32_t bits[8192];          // 32 KB
  __shared__ __align__(16) uint32_t dur[TX_];            // 1 KB

  const float4* gb4   = (const float4*)(lpT + (size_t)b * TY_ * TX_);
  const float4* ring4 = (const float4*)ring;

  // ---- prologue: producers stage chunks 0 (slot 0) and 1 (slot 1) ----
  if (w != 0) {
    const int p = w - 1;                  // 0..2
#pragma unroll
    for (int c = 0; c < 2; ++c) {
      float4 tmp[11];
#pragma unroll
      for (int i = 0; i < 11; ++i) {
        int r = p + 3 * i;
        if (r < 32) tmp[i] = gb4[(size_t)(c * 32 + r) * 64 + lane];
      }
      float4* dst = (float4*)&ring[c * 32 * 256];
#pragma unroll
      for (int i = 0; i < 11; ++i) {
        int r = p + 3 * i;
        if (r < 32) dst[r * 64 + lane] = tmp[i];
      }
    }
  }
  __syncthreads();

  // consumer state (harmless for producers)
  float v0 = (lane == 0) ? 0.0f : NEGF;
  float v1 = NEGF, v2 = NEGF, v3 = NEGF;
  uint32_t w0 = 0, w1 = 0, w2 = 0, w3 = 0;
  float4 rr[4];
#pragma unroll
  for (int i = 0; i < 4; ++i) rr[i] = ring4[i * 64 + lane];  // chunk0 rows 0..3

  int sA = 0, sB = 1;
  for (int g = 0; g < 32; ++g) {
    if (w == 0) {
      const float4* bA = ring4 + sA * 2048;   // chunk g
      const float4* bB = ring4 + sB * 2048;   // chunk g+1 (ready since round g-1)
#pragma unroll
      for (int u = 0; u < 32; ++u) {
        float4 col = rr[u & 3];
        if (u < 28) rr[u & 3] = bA[(u + 4) * 64 + lane];
        else        rr[u & 3] = bB[(u - 28) * 64 + lane];

        float sh = dpp_shr1_negfill_f32(v3);     // old v[x-1] for j=0
        float m0 = fmaxf(v0, sh);
        float m1 = fmaxf(v1, v0);
        float m2 = fmaxf(v2, v1);
        float m3 = fmaxf(v3, v2);
        // diag = (shift > v) strictly  <=>  v - m < 0
        w0 |= (__float_as_uint(v0 - m0) >> 31) << u;
        w1 |= (__float_as_uint(v1 - m1) >> 31) << u;
        w2 |= (__float_as_uint(v2 - m2) >> 31) << u;
        w3 |= (__float_as_uint(v3 - m3) >> 31) << u;
        v0 = col.x + m0;
        v1 = col.y + m1;
        v2 = col.z + m2;
        v3 = col.w + m3;
      }
      // flush this 32-step group's diag words: bits[g][4*lane .. 4*lane+3]
      *(uint4*)&bits[g * 256 + 4 * lane] = make_uint4(w0, w1, w2, w3);
      w0 = w1 = w2 = w3 = 0;
    } else if (g + 2 < 32) {
      // producers stage chunk g+2 into slot (g+2)%3
      const int p = w - 1;
      const int cbase = (g + 2) * 32;
      float4* dst = (float4*)&ring[((g + 2) % 3) * 32 * 256];
      float4 tmp[11];
#pragma unroll
      for (int i = 0; i < 11; ++i) {
        int r = p + 3 * i;
        if (r < 32) tmp[i] = gb4[(size_t)(cbase + r) * 64 + lane];
      }
#pragma unroll
      for (int i = 0; i < 11; ++i) {
        int r = p + 3 * i;
        if (r < 32) dst[r * 64 + lane] = tmp[i];
      }
    }
    __syncthreads();
    sA = sB; sB = (sB == 2) ? 0 : sB + 1;
  }

  dur[tid] = 0;
  __syncthreads();

  const int xlen = xlp[b], ylen = ylp[b];
  if (tid == 0) {
    int idx = xlen - 1;
    int t = ylen - 1;
    while (t >= 0) {
      if (idx == 0) { dur[0] = (uint32_t)(t + 1); break; }
      int ww = t >> 5, rrm = t & 31;
      uint32_t wd = bits[ww * 256 + idx];
      wd &= (rrm == 31) ? 0xffffffffu : ((1u << (rrm + 1)) - 1u);
      while (wd == 0 && ww > 0) { --ww; wd = bits[ww * 256 + idx]; }
      if (wd == 0) { dur[idx] = (uint32_t)(t + 1); break; }
      int bitpos = 31 - __builtin_clz(wd);
      int tp = (ww << 5) | bitpos;       // step where diag fires -> decrement
      dur[idx] = (uint32_t)(t - tp + 1); // first visit of idx -> plain store
      --idx;
      t = tp - 1;
    }
  }
  __syncthreads();

  if (w == 0) {
    // wave-wide inclusive scan of durations -> cum, dr, and t->x scatter map
    uint32_t d0 = dur[4 * lane], d1 = dur[4 * lane + 1];
    uint32_t d2 = dur[4 * lane + 2], d3 = dur[4 * lane + 3];
    uint32_t own = d0 + d1 + d2 + d3;
    uint32_t s = own;
#pragma unroll
    for (int off = 1; off < 64; off <<= 1) {
      uint32_t n = __shfl_up(s, off);
      if (lane >= off) s += n;
    }
    uint32_t base = s - own;
    uint32_t c0 = base + d0, c1 = c0 + d1, c2 = c1 + d2, c3 = c2 + d3;
    int x = 4 * lane;
    cum_ws[b * TX_ + x]     = (int)c0;
    cum_ws[b * TX_ + x + 1] = (int)c1;
    cum_ws[b * TX_ + x + 2] = (int)c2;
    cum_ws[b * TX_ + x + 3] = (int)c3;
    dr_out[b * TX_ + x]     = (float)d0;
    dr_out[b * TX_ + x + 1] = (float)d1;
    dr_out[b * TX_ + x + 2] = (float)d2;
    dr_out[b * TX_ + x + 3] = (float)d3;
    int* xt = xt_ws + b * TY_;
    for (uint32_t t = c0 - d0; t < c0; ++t) xt[t] = x;
    for (uint32_t t = c1 - d1; t < c1; ++t) xt[t] = x + 1;
    for (uint32_t t = c2 - d2; t < c2; ++t) xt[t] = x + 2;
    for (uint32_t t = c3 - d3; t < c3; ++t) xt[t] = x + 3;
  }
}

// ---------------------------------------------------------------------------
// Kernel C (fused epilogue): blocks [0,TX) write attn rows from cum;
// blocks [TX,TX+H) gather o_en_ex[b,h,t] = t<ylen ? en[b,h,xt[b,t]] : 0.
// ---------------------------------------------------------------------------
__global__ __launch_bounds__(256) void k_epi(
    const int* __restrict__ cum_ws, const int* __restrict__ xt_ws,
    const float* __restrict__ en, const int* __restrict__ ylp,
    float* __restrict__ attn, float* __restrict__ oen)
{
  const int b = blockIdx.y, bx = blockIdx.x, tid = threadIdx.x;
  __shared__ float row[TX_];
  if (bx < TX_) {
    const int x = bx;
    int hi = cum_ws[b * TX_ + x];
    int lo = (x > 0) ? cum_ws[b * TX_ + x - 1] : 0;
    int t0 = tid * 4;
    float4 v;
    v.x = (t0     >= lo && t0     < hi) ? 1.f : 0.f;
    v.y = (t0 + 1 >= lo && t0 + 1 < hi) ? 1.f : 0.f;
    v.z = (t0 + 2 >= lo && t0 + 2 < hi) ? 1.f : 0.f;
    v.w = (t0 + 3 >= lo && t0 + 3 < hi) ? 1.f : 0.f;
    *(float4*)&attn[((size_t)(b * TX_ + x)) * TY_ + t0] = v;
  } else {
    const int h = bx - TX_;
    row[tid] = en[((size_t)(b * H_ + h)) * TX_ + tid];
    __syncthreads();
    const int ylen = ylp[b];
    int t0 = tid * 4;
    int4 xi = *(const int4*)&xt_ws[b * TY_ + t0];
    float4 v;
    v.x = (t0     < ylen) ? row[xi.x & (TX_ - 1)] : 0.f;
    v.y = (t0 + 1 < ylen) ? row[xi.y & (TX_ - 1)] : 0.f;
    v.z = (t0 + 2 < ylen) ? row[xi.z & (TX_ - 1)] : 0.f;
    v.w = (t0 + 3 < ylen) ? row[xi.w & (TX_ - 1)] : 0.f;
    *(float4*)&oen[((size_t)(b * H_ + h)) * TY_ + t0] = v;
  }
}

extern "C" void kernel_launch(void* const* d_in, const int* in_sizes, int n_in,
                              void* d_out, int out_size, void* d_ws, size_t ws_size,
                              hipStream_t stream)
{
  const float* en = (const float*)d_in[0];
  const float* mu = (const float*)d_in[1];
  const float* ls = (const float*)d_in[2];
  const float* y  = (const float*)d_in[3];
  const int*   xl = (const int*)d_in[4];
  const int*   yl = (const int*)d_in[5];

  float* out  = (float*)d_out;
  float* oen  = out;             // [B,H,TY]
  float* logp = out + OFF_LOGP;  // [B,TX,TY]
  float* attn = out + OFF_ATTN;  // [B,TX,TY] (doubles as lpT scratch first)
  float* dr   = out + OFF_DR;    // [B,TX]

  int* cum = (int*)d_ws;               // B*TX ints
  int* xt  = cum + B_ * TX_;           // B*TY ints

  k_logp<<<dim3(TX_ / 4, B_),   256, 0, stream>>>(mu, ls, y, xl, yl, logp, attn);
  k_dp  <<<B_,                  256, 0, stream>>>(attn, xl, yl, dr, cum, xt);
  k_epi <<<dim3(TX_ + H_, B_),  256, 0, stream>>>(cum, xt, en, yl, attn, oen);
}

// Round 3
// 179.952 us; speedup vs baseline: 1.3460x; 1.3460x over previous
//
#include <hip/hip_runtime.h>
#include <cstdint>
#include <cmath>

#define B_ 4
#define H_ 256
#define C_ 80
#define TX_ 256
#define TY_ 1024
#define NEGF (-1e9f)

// output layout (floats): o_en_ex [B,H,TY] | logp [B,TX,TY] | attn [B,TX,TY] | dr [B,TX]
#define OFF_LOGP (B_*H_*TY_)
#define OFF_ATTN (OFF_LOGP + B_*TX_*TY_)
#define OFF_DR   (OFF_ATTN + B_*TX_*TY_)

// __shfl_up(x,1) as pure VALU: DPP wave_shr:1 (ctrl 0x138); lane 0 gets NEGF.
__device__ __forceinline__ float dpp_shr1_negfill_f32(float x) {
  union { float f; int i; } u, o, r;
  u.f = x; o.f = NEGF;
  r.i = __builtin_amdgcn_update_dpp(o.i, u.i, 0x138, 0xf, 0xf, false);
  return r.f;
}

// ---------------------------------------------------------------------------
// Kernel A: logp (unchanged, passing since R5).
// ---------------------------------------------------------------------------
__global__ __launch_bounds__(256) void k_logp(
    const float* __restrict__ mu, const float* __restrict__ ls,
    const float* __restrict__ y, const int* __restrict__ xlp,
    const int* __restrict__ ylp, float* __restrict__ logp_out,
    float* __restrict__ lpT)
{
  const int b  = blockIdx.y;
  const int x0 = blockIdx.x * 4;
  const int tid = threadIdx.x;
  __shared__ double s_w[4][C_];
  __shared__ double s_m1[4][C_];
  __shared__ double s_wm2[4][C_];
  __shared__ double s_lsv[4][C_];
  __shared__ double s_K[4];
  __shared__ double s_t0[4];
  __shared__ float tile[TY_][4];
  for (int i = tid; i < 4 * C_; i += 256) {
    int xi = i / C_, c = i - xi * C_;
    double m = (double)mu[(b * C_ + c) * TX_ + x0 + xi];
    double l = (double)ls[(b * C_ + c) * TX_ + x0 + xi];
    double w = exp(-2.0 * l);
    s_w[xi][c]   = w;
    s_m1[xi][c]  = -2.0 * w * m;
    s_wm2[xi][c] = w * m * m;
    s_lsv[xi][c] = l;
  }
  __syncthreads();
  {
    int xi = tid >> 6, cc = tid & 63;
    double kp = (cc < C_) ? s_wm2[xi][cc] : 0.0;
    double tp = (cc < C_) ? s_lsv[xi][cc] : 0.0;
    if (cc + 64 < C_) { kp += s_wm2[xi][cc + 64]; tp += s_lsv[xi][cc + 64]; }
#pragma unroll
    for (int off = 32; off; off >>= 1) {
      kp += __shfl_down(kp, off);
      tp += __shfl_down(tp, off);
    }
    if (cc == 0) { s_K[xi] = kp; s_t0[xi] = -0.5 * (tp * (1.0 / C_)); }
  }
  __syncthreads();

  const int t0 = tid * 4;
  double acc[4][4];
#pragma unroll
  for (int xi = 0; xi < 4; ++xi)
#pragma unroll
    for (int k = 0; k < 4; ++k) acc[xi][k] = 0.0;

  const float4* yp = (const float4*)(y + (size_t)b * C_ * TY_) + tid;
#pragma unroll 4
  for (int c = 0; c < C_; ++c) {
    float4 yv = yp[c * (TY_ / 4)];
    double y0 = yv.x, y1 = yv.y, y2 = yv.z, y3 = yv.w;
#pragma unroll
    for (int xi = 0; xi < 4; ++xi) {
      double w = s_w[xi][c], m1 = s_m1[xi][c];
      double u0 = fma(w, y0, m1), u1 = fma(w, y1, m1);
      double u2 = fma(w, y2, m1), u3 = fma(w, y3, m1);
      acc[xi][0] = fma(u0, y0, acc[xi][0]);
      acc[xi][1] = fma(u1, y1, acc[xi][1]);
      acc[xi][2] = fma(u2, y2, acc[xi][2]);
      acc[xi][3] = fma(u3, y3, acc[xi][3]);
    }
  }

  const int xlen = xlp[b], ylen = ylp[b];
#pragma unroll
  for (int xi = 0; xi < 4; ++xi) {
    int x = x0 + xi;
    double c0 = s_t0[xi], K = s_K[xi];
    float r[4];
#pragma unroll
    for (int k = 0; k < 4; ++k)
      r[k] = (float)((acc[xi][k] + K) * (-0.5 / C_) + c0);
    *(float4*)&logp_out[((size_t)(b * TX_ + x)) * TY_ + t0] =
        make_float4(r[0], r[1], r[2], r[3]);
    bool xm = x < xlen;
#pragma unroll
    for (int k = 0; k < 4; ++k)
      tile[t0 + k][xi] = (xm && (t0 + k) < ylen) ? r[k] : NEGF;
  }
  __syncthreads();

  float* dst = lpT + (size_t)b * TY_ * TX_ + x0;
  const float4* tp = (const float4*)tile;
#pragma unroll
  for (int k = 0; k < 4; ++k) {
    int t = tid + 256 * k;
    *(float4*)&dst[(size_t)t * TX_] = tp[t];
  }
}

// ---------------------------------------------------------------------------
// Kernel B (R16): barrier-free producer-consumer Viterbi DP.
//
// R15 post-mortem: per-round __syncthreads turned pipeline slack into serial
// latency -- every 32 steps paid consumer-compute THEN producer-load-latency
// back to back (10.8k cyc/round).  R14 showed a single wave is limited by its
// own VMEM path (~16 lines ~ 130 cyc per 1KB row).  Fix: keep the role split
// but delete all barriers from the main loop.  Sync = LDS flags (one per
// 16-row chunk) + consumer progress counter, spin with s_sleep.  Producers
// free-run up to 6 chunks ahead (6-slot x 16-row ring, 96KB) so global-load
// latency is absorbed by slack, never by the consumer.
//
// Ordering: producer does ds_writes -> s_waitcnt lgkmcnt(0) -> flag store
// (DS FIFO per wave => flag visible implies data visible).  Consumer polls
// a volatile LDS flag + compiler memory barrier (no hoisting of data reads).
// Deadlock-free: producer of chunk c waits prog >= c-6 (the slot's previous
// tenant c-6 is fully read once prog = c-6); chunks 0..5 start immediately.
//
// ylen cut: forward runs nch = 2*ceil(ylen/32) chunks (<= 64) instead of a
// fixed 64 -- bits words above ylen-1 are never read by the backtrack.
//
// Math bit-identical to R14/R15: m = fmaxf(v, sh); nv = col + m;
// diag bit = signbit(v - m) <=> (sh > v) strict.  bits layout unchanged;
// backtrack/scan/scatter carried over verbatim.
// LDS: ring 96KB + bits 32KB + dur 1KB + flags 0.3KB = 129.3KB.
// ---------------------------------------------------------------------------
#define POLL_FLAG(i)                                                     \
  { while (vflag[i] == 0u) __builtin_amdgcn_s_sleep(1);                  \
    asm volatile("" ::: "memory"); }

#define DP_CHUNK(SHBASE)                                                 \
  _Pragma("unroll")                                                      \
  for (int u = 0; u < 16; ++u) {                                         \
    float4 col = rr[u & 7];                                              \
    rr[u & 7] = (u < 8) ? pA[(u + 8) * 64 + lane]                        \
                        : pB[(u - 8) * 64 + lane];                       \
    float sh = dpp_shr1_negfill_f32(v3);                                 \
    float m0 = fmaxf(v0, sh);                                            \
    float m1 = fmaxf(v1, v0);                                            \
    float m2 = fmaxf(v2, v1);                                            \
    float m3 = fmaxf(v3, v2);                                            \
    w0 |= (__float_as_uint(v0 - m0) >> 31) << ((SHBASE) + u);            \
    w1 |= (__float_as_uint(v1 - m1) >> 31) << ((SHBASE) + u);            \
    w2 |= (__float_as_uint(v2 - m2) >> 31) << ((SHBASE) + u);            \
    w3 |= (__float_as_uint(v3 - m3) >> 31) << ((SHBASE) + u);            \
    v0 = col.x + m0;                                                     \
    v1 = col.y + m1;                                                     \
    v2 = col.z + m2;                                                     \
    v3 = col.w + m3;                                                     \
  }

__global__ __launch_bounds__(256, 1) void k_dp(
    const float* __restrict__ lpT, const int* __restrict__ xlp,
    const int* __restrict__ ylp, float* __restrict__ dr_out,
    int* __restrict__ cum_ws, int* __restrict__ xt_ws)
{
  const int b = blockIdx.x;
  const int tid = threadIdx.x;
  const int lane = tid & 63;
  const int w = tid >> 6;                 // 0 = consumer, 1..3 = producers
  __shared__ __align__(16) float    ring[6 * 16 * 256];  // 96 KB, 6 slots
  __shared__ __align__(16) uint32_t bits[8192];          // 32 KB
  __shared__ __align__(16) uint32_t dur[TX_];            // 1 KB
  __shared__ uint32_t flags[64];
  __shared__ int      prog;

  const float4* gb4   = (const float4*)(lpT + (size_t)b * TY_ * TX_);
  const float4* ring4 = (const float4*)ring;

  const int ylen = ylp[b];
  const int nch  = ((ylen + 31) >> 5) << 1;   // even # of 16-row chunks, 32..64

  if (tid < 64) flags[tid] = 0u;
  if (tid == 0) prog = -1;
  __syncthreads();

  if (w == 0) {
    // ---------------- consumer: pure LDS + VALU DP ----------------
    volatile uint32_t* vflag = flags;
    volatile int*      vprog = &prog;
    POLL_FLAG(0);
    float4 rr[8];
#pragma unroll
    for (int i = 0; i < 8; ++i) rr[i] = ring4[i * 64 + lane];  // slot0 rows 0..7

    float v0 = (lane == 0) ? 0.0f : NEGF;
    float v1 = NEGF, v2 = NEGF, v3 = NEGF;
    uint32_t w0 = 0, w1 = 0, w2 = 0, w3 = 0;
    int sA = 0, sB = 1;
    const float4* pA;
    const float4* pB;

    for (int cp = 0; cp < nch; cp += 2) {
      { int nf = (cp + 1 < nch) ? cp + 1 : nch - 1; POLL_FLAG(nf); }
      pA = ring4 + sA * 1024; pB = ring4 + sB * 1024;
      DP_CHUNK(0)
      asm volatile("" ::: "memory");
      *vprog = cp;
      sA = sB; sB = (sB == 5) ? 0 : sB + 1;

      { int nf = (cp + 2 < nch) ? cp + 2 : nch - 1; POLL_FLAG(nf); }
      pA = ring4 + sA * 1024; pB = ring4 + sB * 1024;
      DP_CHUNK(16)
      *(uint4*)&bits[(cp >> 1) * 256 + 4 * lane] = make_uint4(w0, w1, w2, w3);
      w0 = w1 = w2 = w3 = 0;
      asm volatile("" ::: "memory");
      *vprog = cp + 1;
      sA = sB; sB = (sB == 5) ? 0 : sB + 1;
    }
  } else {
    // ---------------- producers: global -> reg -> LDS ring ----------------
    const int p = w - 1;                  // 0..2, handles chunks c ≡ p (mod 3)
    volatile int*      vprog = &prog;
    volatile uint32_t* vflag = flags;
    for (int c = p; c < nch; c += 3) {
      const int need = c - 6;             // slot tenant c-6 must be consumed
      while (*vprog < need) __builtin_amdgcn_s_sleep(8);
      asm volatile("" ::: "memory");
      const float4* src = gb4 + (size_t)(c * 16) * 64 + lane;
      float4 tmp[16];
#pragma unroll
      for (int r = 0; r < 16; ++r) tmp[r] = src[r * 64];
      float4* dst = (float4*)&ring[(c % 6) * 4096] + lane;
#pragma unroll
      for (int r = 0; r < 16; ++r) dst[r * 64] = tmp[r];
      asm volatile("s_waitcnt lgkmcnt(0)" ::: "memory");
      vflag[c] = 1u;
    }
  }

  __syncthreads();
  dur[tid] = 0;
  __syncthreads();

  const int xlen = xlp[b];
  if (tid == 0) {
    int idx = xlen - 1;
    int t = ylen - 1;
    while (t >= 0) {
      if (idx == 0) { dur[0] = (uint32_t)(t + 1); break; }
      int ww = t >> 5, rrm = t & 31;
      uint32_t wd = bits[ww * 256 + idx];
      wd &= (rrm == 31) ? 0xffffffffu : ((1u << (rrm + 1)) - 1u);
      while (wd == 0 && ww > 0) { --ww; wd = bits[ww * 256 + idx]; }
      if (wd == 0) { dur[idx] = (uint32_t)(t + 1); break; }
      int bitpos = 31 - __builtin_clz(wd);
      int tp = (ww << 5) | bitpos;       // step where diag fires -> decrement
      dur[idx] = (uint32_t)(t - tp + 1); // first visit of idx -> plain store
      --idx;
      t = tp - 1;
    }
  }
  __syncthreads();

  if (w == 0) {
    // wave-wide inclusive scan of durations -> cum, dr, and t->x scatter map
    uint32_t d0 = dur[4 * lane], d1 = dur[4 * lane + 1];
    uint32_t d2 = dur[4 * lane + 2], d3 = dur[4 * lane + 3];
    uint32_t own = d0 + d1 + d2 + d3;
    uint32_t s = own;
#pragma unroll
    for (int off = 1; off < 64; off <<= 1) {
      uint32_t n = __shfl_up(s, off);
      if (lane >= off) s += n;
    }
    uint32_t base = s - own;
    uint32_t c0 = base + d0, c1 = c0 + d1, c2 = c1 + d2, c3 = c2 + d3;
    int x = 4 * lane;
    cum_ws[b * TX_ + x]     = (int)c0;
    cum_ws[b * TX_ + x + 1] = (int)c1;
    cum_ws[b * TX_ + x + 2] = (int)c2;
    cum_ws[b * TX_ + x + 3] = (int)c3;
    dr_out[b * TX_ + x]     = (float)d0;
    dr_out[b * TX_ + x + 1] = (float)d1;
    dr_out[b * TX_ + x + 2] = (float)d2;
    dr_out[b * TX_ + x + 3] = (float)d3;
    int* xt = xt_ws + b * TY_;
    for (uint32_t t = c0 - d0; t < c0; ++t) xt[t] = x;
    for (uint32_t t = c1 - d1; t < c1; ++t) xt[t] = x + 1;
    for (uint32_t t = c2 - d2; t < c2; ++t) xt[t] = x + 2;
    for (uint32_t t = c3 - d3; t < c3; ++t) xt[t] = x + 3;
  }
}

// ---------------------------------------------------------------------------
// Kernel C (fused epilogue): blocks [0,TX) write attn rows from cum;
// blocks [TX,TX+H) gather o_en_ex[b,h,t] = t<ylen ? en[b,h,xt[b,t]] : 0.
// ---------------------------------------------------------------------------
__global__ __launch_bounds__(256) void k_epi(
    const int* __restrict__ cum_ws, const int* __restrict__ xt_ws,
    const float* __restrict__ en, const int* __restrict__ ylp,
    float* __restrict__ attn, float* __restrict__ oen)
{
  const int b = blockIdx.y, bx = blockIdx.x, tid = threadIdx.x;
  __shared__ float row[TX_];
  if (bx < TX_) {
    const int x = bx;
    int hi = cum_ws[b * TX_ + x];
    int lo = (x > 0) ? cum_ws[b * TX_ + x - 1] : 0;
    int t0 = tid * 4;
    float4 v;
    v.x = (t0     >= lo && t0     < hi) ? 1.f : 0.f;
    v.y = (t0 + 1 >= lo && t0 + 1 < hi) ? 1.f : 0.f;
    v.z = (t0 + 2 >= lo && t0 + 2 < hi) ? 1.f : 0.f;
    v.w = (t0 + 3 >= lo && t0 + 3 < hi) ? 1.f : 0.f;
    *(float4*)&attn[((size_t)(b * TX_ + x)) * TY_ + t0] = v;
  } else {
    const int h = bx - TX_;
    row[tid] = en[((size_t)(b * H_ + h)) * TX_ + tid];
    __syncthreads();
    const int ylen = ylp[b];
    int t0 = tid * 4;
    int4 xi = *(const int4*)&xt_ws[b * TY_ + t0];
    float4 v;
    v.x = (t0     < ylen) ? row[xi.x & (TX_ - 1)] : 0.f;
    v.y = (t0 + 1 < ylen) ? row[xi.y & (TX_ - 1)] : 0.f;
    v.z = (t0 + 2 < ylen) ? row[xi.z & (TX_ - 1)] : 0.f;
    v.w = (t0 + 3 < ylen) ? row[xi.w & (TX_ - 1)] : 0.f;
    *(float4*)&oen[((size_t)(b * H_ + h)) * TY_ + t0] = v;
  }
}

extern "C" void kernel_launch(void* const* d_in, const int* in_sizes, int n_in,
                              void* d_out, int out_size, void* d_ws, size_t ws_size,
                              hipStream_t stream)
{
  const float* en = (const float*)d_in[0];
  const float* mu = (const float*)d_in[1];
  const float* ls = (const float*)d_in[2];
  const float* y  = (const float*)d_in[3];
  const int*   xl = (const int*)d_in[4];
  const int*   yl = (const int*)d_in[5];

  float* out  = (float*)d_out;
  float* oen  = out;             // [B,H,TY]
  float* logp = out + OFF_LOGP;  // [B,TX,TY]
  float* attn = out + OFF_ATTN;  // [B,TX,TY] (doubles as lpT scratch first)
  float* dr   = out + OFF_DR;    // [B,TX]

  int* cum = (int*)d_ws;               // B*TX ints
  int* xt  = cum + B_ * TX_;           // B*TY ints

  k_logp<<<dim3(TX_ / 4, B_),   256, 0, stream>>>(mu, ls, y, xl, yl, logp, attn);
  k_dp  <<<B_,                  256, 0, stream>>>(attn, xl, yl, dr, cum, xt);
  k_epi <<<dim3(TX_ + H_, B_),  256, 0, stream>>>(cum, xt, en, yl, attn, oen);
}